// Round 1
// baseline (879.825 us; speedup 1.0000x reference)
//
#include <hip/hip_runtime.h>
#include <math.h>

namespace {

constexpr int NB = 64;             // batch rows
constexpr int NL = 480000;         // samples per row
constexpr int CHUNK = 1920;        // payload per block (multiple of 64)
constexpr int WARM = 32768;        // warm-up samples (multiple of 64)
constexpr int NBLK = NL / CHUNK;   // 250 blocks
constexpr int TS = 64;             // tile steps
constexpr int INSTRIDE = 65;       // lds_in row stride in floats ([t][b] padded)
constexpr int OUTSTRIDE = 17;      // lds_out row stride in float4 ([b][q] padded)

typedef float v2f __attribute__((ext_vector_type(2)));

__global__ __launch_bounds__(64, 1)
void envfollow_kernel(const float* __restrict__ x,
                      const float* __restrict__ p_ra,
                      const float* __restrict__ p_rr,
                      const int* __restrict__ p_sr,
                      float* __restrict__ out)
{
    __shared__ float  lds_in[2][TS * INSTRIDE];
    __shared__ float4 lds_out[NB * OUTSTRIDE];

    const int lane = threadIdx.x;          // lane == the batch row it scans
    const int c    = blockIdx.x;
    const int pay_begin = c * CHUNK;
    const int pay_end   = pay_begin + CHUNK;
    int t0 = pay_begin - WARM;
    if (t0 < 0) t0 = 0;                    // 64-aligned either way

    // coefficients (match reference fp32 math)
    const float sr   = (float)p_sr[0];
    const float siga = 1.0f / (1.0f + expf(-p_ra[0]));
    const float sigr = 1.0f / (1.0f + expf(-p_rr[0]));
    const float attack_ms  = 0.1f  + siga * 49.9f;
    const float release_ms = 10.0f + sigr * 490.0f;
    const float ca = expf(-1000.0f / (attack_ms  * sr));
    const float cr = expf(-1000.0f / (release_ms * sr));
    const float oma = 1.0f - ca;
    const float omr = 1.0f - cr;

    const int lr = lane >> 4;              // row sub-group 0..3
    const int lc = (lane & 15) << 2;       // col offset 0..60

    float4 regs[16];                       // staged tile (global -> regs -> LDS)

    float env = 0.0f;
    int buf = 0;

    // ---- prologue: load + stage first tile into buf 0 ----
    {
#pragma unroll
        for (int g = 0; g < 16; ++g) {
            const int row = g * 4 + lr;
            regs[g] = *reinterpret_cast<const float4*>(
                &x[(size_t)row * NL + (t0 + lc)]);
        }
        float* dst = lds_in[0];
#pragma unroll
        for (int g = 0; g < 16; ++g) {
            const int row = g * 4 + lr;
            dst[(lc + 0) * INSTRIDE + row] = fabsf(regs[g].x);
            dst[(lc + 1) * INSTRIDE + row] = fabsf(regs[g].y);
            dst[(lc + 2) * INSTRIDE + row] = fabsf(regs[g].z);
            dst[(lc + 3) * INSTRIDE + row] = fabsf(regs[g].w);
        }
    }

    for (int tb = t0; tb < pay_end; tb += TS) {
        const bool more = (tb + TS) < pay_end;

        // issue next tile's global loads early; latency hides under the scan
        if (more) {
#pragma unroll
            for (int g = 0; g < 16; ++g) {
                const int row = g * 4 + lr;
                regs[g] = *reinterpret_cast<const float4*>(
                    &x[(size_t)row * NL + (tb + TS + lc)]);
            }
        }

        // ---- serial scan of 64 steps from lds_in[buf] ----
        {
            const float* src = lds_in[buf] + lane;
            float4 oacc;
            const v2f cf = {ca, cr};
            const v2f om = {oma, omr};
#pragma unroll
            for (int j = 0; j < TS; ++j) {
                const float l = src[j * INSTRIDE];   // |x| staged at write time
                v2f lv; lv[0] = l;   lv[1] = l;
                v2f ev; ev[0] = env; ev[1] = env;
                const v2f ofs = om * lv;                       // ((1-a)l,(1-r)l)
                const v2f f = __builtin_elementwise_fma(cf, ev, ofs);
                env = fmaxf(f[0], f[1]);   // max picks the correct branch exactly
                if ((j & 3) == 0)      oacc.x = env;
                else if ((j & 3) == 1) oacc.y = env;
                else if ((j & 3) == 2) oacc.z = env;
                else {
                    oacc.w = env;
                    lds_out[lane * OUTSTRIDE + (j >> 2)] = oacc;
                }
            }
        }

        // ---- coalesced store of the payload tile ----
        if (tb >= pay_begin) {
#pragma unroll
            for (int g = 0; g < 16; ++g) {
                const int row = g * 4 + lr;
                const float4 v = lds_out[row * OUTSTRIDE + (lane & 15)];
                *reinterpret_cast<float4*>(
                    &out[(size_t)row * NL + (tb + lc)]) = v;
            }
        }

        // ---- stage the prefetched tile into the other buffer ----
        if (more) {
            float* dst = lds_in[buf ^ 1];
#pragma unroll
            for (int g = 0; g < 16; ++g) {
                const int row = g * 4 + lr;
                dst[(lc + 0) * INSTRIDE + row] = fabsf(regs[g].x);
                dst[(lc + 1) * INSTRIDE + row] = fabsf(regs[g].y);
                dst[(lc + 2) * INSTRIDE + row] = fabsf(regs[g].z);
                dst[(lc + 3) * INSTRIDE + row] = fabsf(regs[g].w);
            }
        }
        buf ^= 1;
    }
}

} // namespace

extern "C" void kernel_launch(void* const* d_in, const int* in_sizes, int n_in,
                              void* d_out, int out_size, void* d_ws, size_t ws_size,
                              hipStream_t stream)
{
    const float* x   = (const float*)d_in[0];
    const float* ra  = (const float*)d_in[1];
    const float* rr  = (const float*)d_in[2];
    const int*   srp = (const int*)d_in[3];
    float* out = (float*)d_out;

    hipLaunchKernelGGL(envfollow_kernel, dim3(NBLK), dim3(64), 0, stream,
                       x, ra, rr, srp, out);
}